// Round 12
// baseline (258.675 us; speedup 1.0000x reference)
//
#include <hip/hip_runtime.h>

#define N_NODES 4096
#define IN_FEAT 256
#define N_HEADS 8
#define N_HIDDEN 64
#define OUT_FEAT (N_HEADS * N_HIDDEN)  // 512
#define NEG_SLOPE 0.2f

typedef _Float16 half8 __attribute__((ext_vector_type(8)));
typedef _Float16 h2 __attribute__((ext_vector_type(2)));
typedef float floatx4 __attribute__((ext_vector_type(4)));

// ---------------- fat producer: MFMA GEMM + epilogue | adj->bits ----------
// (validated R8-R10 kernel, unchanged)
__global__ __launch_bounds__(256) void produce(
    const float* __restrict__ H, const float* __restrict__ adj,
    const float* __restrict__ Wt, const float* __restrict__ a,
    _Float16* __restrict__ GT16, float* __restrict__ elT,
    _Float16* __restrict__ eR1h, _Float16* __restrict__ eR2h,
    unsigned long long* __restrict__ bits) {
  __shared__ _Float16 SM[4 * 64 * 64];  // 32 KB: Ah|Al|Bh|Bl
  const int t = threadIdx.x;
  const int bx = blockIdx.x, by = blockIdx.y;

  if (by >= 8) {
    const int c = bx * 8 + (by - 8);
    const size_t W0 = (size_t)c * 512;
    const int wv = t >> 6, lane = t & 63;
    for (int k0 = 0; k0 < 128; k0 += 8) {
      float v[8];
#pragma unroll
      for (int k = 0; k < 8; ++k)
        v[k] = adj[(W0 + wv * 128 + k0 + k) * 64 + lane];
#pragma unroll
      for (int k = 0; k < 8; ++k) {
        unsigned long long m = __ballot(v[k] != 0.f);
        if (lane == 0) bits[W0 + wv * 128 + k0 + k] = m;
      }
    }
    return;
  }

  _Float16* Ah = SM;
  _Float16* Al = SM + 4096;
  _Float16* Bh = SM + 8192;
  _Float16* Bl = SM + 12288;
  const int w = t >> 6, l = t & 63;
  const int n16 = l & 15, q = l >> 4;
  const int bi = bx, bo = by;
  const int m0 = bi * 64 + w * 16;

  floatx4 acc[4];
#pragma unroll
  for (int ct = 0; ct < 4; ++ct) acc[ct] = (floatx4)0.f;

  for (int kc = 0; kc < 4; ++kc) {
    if (kc) __syncthreads();
#pragma unroll
    for (int p = 0; p < 4; ++p) {
      const int idx = p * 256 + t;
      const int r = idx >> 4;
      const int c4 = (idx & 15) << 2;
      const int dst = r * 64 + ((((idx & 15) >> 1)) ^ (r & 7)) * 8 + (idx & 1) * 4;
      float4 hv = *(const float4*)(H + (size_t)(bi * 64 + r) * IN_FEAT + kc * 64 + c4);
      float4 wv = *(const float4*)(Wt + (size_t)(bo * 64 + r) * IN_FEAT + kc * 64 + c4);
      union { _Float16 h[4]; int2 d; } hh_, hl_, wh_, wl_;
      hh_.h[0] = (_Float16)hv.x; hh_.h[1] = (_Float16)hv.y;
      hh_.h[2] = (_Float16)hv.z; hh_.h[3] = (_Float16)hv.w;
      hl_.h[0] = (_Float16)(hv.x - (float)hh_.h[0]);
      hl_.h[1] = (_Float16)(hv.y - (float)hh_.h[1]);
      hl_.h[2] = (_Float16)(hv.z - (float)hh_.h[2]);
      hl_.h[3] = (_Float16)(hv.w - (float)hh_.h[3]);
      wh_.h[0] = (_Float16)wv.x; wh_.h[1] = (_Float16)wv.y;
      wh_.h[2] = (_Float16)wv.z; wh_.h[3] = (_Float16)wv.w;
      wl_.h[0] = (_Float16)(wv.x - (float)wh_.h[0]);
      wl_.h[1] = (_Float16)(wv.y - (float)wh_.h[1]);
      wl_.h[2] = (_Float16)(wv.z - (float)wh_.h[2]);
      wl_.h[3] = (_Float16)(wv.w - (float)wh_.h[3]);
      *(int2*)&Ah[dst] = hh_.d;
      *(int2*)&Al[dst] = hl_.d;
      *(int2*)&Bh[dst] = wh_.d;
      *(int2*)&Bl[dst] = wl_.d;
    }
    __syncthreads();
#pragma unroll
    for (int ks = 0; ks < 2; ++ks) {
      const int ao = (w * 16 + n16) * 64 + (((ks << 2) + q) ^ (n16 & 7)) * 8;
      half8 Afh = *(const half8*)&Ah[ao];
      half8 Afl = *(const half8*)&Al[ao];
#pragma unroll
      for (int ct = 0; ct < 4; ++ct) {
        const int bofs = (ct * 16 + n16) * 64 + (((ks << 2) + q) ^ (n16 & 7)) * 8;
        half8 Bfh = *(const half8*)&Bh[bofs];
        half8 Bfl = *(const half8*)&Bl[bofs];
        acc[ct] = __builtin_amdgcn_mfma_f32_16x16x32_f16(Afh, Bfh, acc[ct], 0, 0, 0);
        acc[ct] = __builtin_amdgcn_mfma_f32_16x16x32_f16(Afl, Bfh, acc[ct], 0, 0, 0);
        acc[ct] = __builtin_amdgcn_mfma_f32_16x16x32_f16(Afh, Bfl, acc[ct], 0, 0, 0);
      }
    }
  }

  float aLv[4], aRv[4];
#pragma unroll
  for (int ct = 0; ct < 4; ++ct) {
    aLv[ct] = a[ct * 16 + n16];
    aRv[ct] = a[64 + ct * 16 + n16];
  }
#pragma unroll
  for (int reg = 0; reg < 4; ++reg) {
    float sl = 0.f, sr = 0.f;
#pragma unroll
    for (int ct = 0; ct < 4; ++ct) {
      sl = fmaf(acc[ct][reg], aLv[ct], sl);
      sr = fmaf(acc[ct][reg], aRv[ct], sr);
    }
#pragma unroll
    for (int off = 1; off < 16; off <<= 1) {
      sl += __shfl_xor(sl, off);
      sr += __shfl_xor(sr, off);
    }
    if (n16 == 0) {
      const int rowi = m0 + q * 4 + reg;
      elT[(size_t)bo * N_NODES + rowi] = sl;
      eR1h[(size_t)bo * N_NODES + rowi] = (_Float16)__expf(sr);
      eR2h[(size_t)bo * N_NODES + rowi] = (_Float16)__expf(0.2f * sr);
    }
  }

  __syncthreads();
  _Float16* LG = SM;  // 64 x 72 halfs
#pragma unroll
  for (int ct = 0; ct < 4; ++ct)
#pragma unroll
    for (int reg = 0; reg < 4; ++reg)
      LG[(w * 16 + q * 4 + reg) * 72 + ct * 16 + n16] = (_Float16)acc[ct][reg];
  __syncthreads();
  {
    const int f = t >> 2, jq = t & 3;
    union { _Float16 hh[16]; int4 v[2]; } u;
#pragma unroll
    for (int k = 0; k < 16; ++k) u.hh[k] = LG[(jq * 16 + k) * 72 + f];
    _Float16* dst = GT16 + (size_t)(bo * 64 + f) * N_NODES + bi * 64 + jq * 16;
    *(int4*)dst = u.v[0];
    *(int4*)(dst + 8) = u.v[1];
  }
}

// ---------------- dense attention v7b: barrier-free, direct-global B-frags
// Grid (128 i-tiles, 8 heads), 256 threads = 4 waves: rt=w&1 (16 rows),
// jh=w>>1 (2048 j). No LDS staging in the main loop: B-fragments are global
// loads from the L2-resident GT16 panel (each 64B line fully consumed by 4
// lanes); eR/bits loaded directly; 1-step register prefetch; zero
// __syncthreads over the 32 steps. ALL loop addressing is absolute in
// `step` (R11 bug was a double pointer advance: gb += 64 AND (step+1)*64).
// pk-fp16 P-gen + ones-column Z MFMA + jh-combine epilogue: validated v6.
__global__ __launch_bounds__(256, 4) void attn_v7(
    const unsigned long long* __restrict__ bits, const _Float16* __restrict__ GT16,
    const float* __restrict__ elT, const _Float16* __restrict__ eR1h,
    const _Float16* __restrict__ eR2h, float* __restrict__ out) {
  __shared__ float comb[32 * 68];  // 8.7 KB
  __shared__ float eL1s[32], eL2s[32];
  __shared__ float Zh1[32], Zfull[32];

  const int t = threadIdx.x;
  const int ib = blockIdx.x, h = blockIdx.y;
  const int i0 = ib * 32;
  const int w = t >> 6, l = t & 63, n16 = l & 15, q = l >> 4;
  const int rt = w & 1, jh = w >> 1;

  if (t < 32) {
    float e = elT[(size_t)h * N_NODES + i0 + t];
    eL1s[t] = __expf(e);
    eL2s[t] = __expf(0.2f * e);
  }
  __syncthreads();

  const _Float16 e1f = (_Float16)eL1s[rt * 16 + n16];
  const _Float16 e2f = (_Float16)eL2s[rt * 16 + n16];
  const h2 eL1h2 = {e1f, e1f};
  const h2 eL2h2 = {e2f, e2f};
  half8 Bones;
#pragma unroll
  for (int k = 0; k < 8; ++k) Bones[k] = (n16 == 0) ? (_Float16)1.f : (_Float16)0.f;

  // per-lane base pointers (NEVER advanced; all offsets absolute in step)
  const _Float16* gb = GT16 + (size_t)(h * 64 + n16) * N_NODES + jh * 2048 + q * 8;
  const _Float16* e1p = eR1h + (size_t)h * N_NODES + jh * 2048 + q * 8;
  const _Float16* e2p = eR2h + (size_t)h * N_NODES + jh * 2048 + q * 8;
  const unsigned long long* bp = bits + (size_t)(i0 + rt * 16 + n16) * 64 + jh * 32;

  floatx4 acc[4];
#pragma unroll
  for (int ft = 0; ft < 4; ++ft) acc[ft] = (floatx4)0.f;
  floatx4 acc5 = (floatx4)0.f;

  // ---- prefetch step 0 ----
  half8 Bc[2][4];
  uint4 r1c[2], r2c[2];
  unsigned long long bvc;
#pragma unroll
  for (int ks = 0; ks < 2; ++ks) {
#pragma unroll
    for (int ft = 0; ft < 4; ++ft)
      Bc[ks][ft] = *(const half8*)(gb + (size_t)ft * (16 * N_NODES) + ks * 32);
    r1c[ks] = *(const uint4*)(e1p + ks * 32);
    r2c[ks] = *(const uint4*)(e2p + ks * 32);
  }
  bvc = bp[0];

  for (int step = 0; step < 32; ++step) {
    // ---- prefetch step+1 into "next" regs (absolute offsets) ----
    half8 Bn[2][4];
    uint4 r1n[2], r2n[2];
    unsigned long long bvn = bvc;
    if (step + 1 < 32) {
      const _Float16* gs = gb + (step + 1) * 64;
#pragma unroll
      for (int ks = 0; ks < 2; ++ks) {
#pragma unroll
        for (int ft = 0; ft < 4; ++ft)
          Bn[ks][ft] = *(const half8*)(gs + (size_t)ft * (16 * N_NODES) + ks * 32);
        r1n[ks] = *(const uint4*)(e1p + (step + 1) * 64 + ks * 32);
        r2n[ks] = *(const uint4*)(e2p + (step + 1) * 64 + ks * 32);
      }
      bvn = bp[step + 1];
    }
    // ---- compute current step ----
#pragma unroll
    for (int ks = 0; ks < 2; ++ks) {
      const unsigned dw = (unsigned)(bvc >> (ks * 32));
      const unsigned byte = (dw >> (q * 8)) & 0xffu;
      const unsigned r1a[4] = {r1c[ks].x, r1c[ks].y, r1c[ks].z, r1c[ks].w};
      const unsigned r2a[4] = {r2c[ks].x, r2c[ks].y, r2c[ks].z, r2c[ks].w};
      unsigned pr[4];
#pragma unroll
      for (int kk = 0; kk < 4; ++kk) {
        h2 pa = eL1h2 * __builtin_bit_cast(h2, r1a[kk]);
        h2 pb = eL2h2 * __builtin_bit_cast(h2, r2a[kk]);
        h2 pv = __builtin_elementwise_max(pa, pb);
        unsigned y = (byte >> (2 * kk)) & 3u;
        unsigned b01 = (y | (y << 15)) & 0x00010001u;
        unsigned keep = b01 * 0xffffu;
        pr[kk] = (__builtin_bit_cast(unsigned, pv) & keep) | (0x3C003C00u & ~keep);
      }
      const uint4 prv = {pr[0], pr[1], pr[2], pr[3]};
      half8 Af = __builtin_bit_cast(half8, prv);
#pragma unroll
      for (int ft = 0; ft < 4; ++ft)
        acc[ft] = __builtin_amdgcn_mfma_f32_16x16x32_f16(Af, Bc[ks][ft], acc[ft], 0, 0, 0);
      acc5 = __builtin_amdgcn_mfma_f32_16x16x32_f16(Af, Bones, acc5, 0, 0, 0);
    }
    // ---- rotate prefetch ----
#pragma unroll
    for (int ks = 0; ks < 2; ++ks) {
#pragma unroll
      for (int ft = 0; ft < 4; ++ft) Bc[ks][ft] = Bn[ks][ft];
      r1c[ks] = r1n[ks];
      r2c[ks] = r2n[ks];
    }
    bvc = bvn;
  }

  // ---- combine j-halves, normalize, store (validated v6 epilogue) ----
  if (jh == 1) {
#pragma unroll
    for (int ft = 0; ft < 4; ++ft)
#pragma unroll
      for (int reg = 0; reg < 4; ++reg)
        comb[(rt * 16 + q * 4 + reg) * 68 + ft * 16 + n16] = acc[ft][reg];
    if (n16 == 0) {
#pragma unroll
      for (int reg = 0; reg < 4; ++reg) Zh1[rt * 16 + q * 4 + reg] = acc5[reg];
    }
  }
  __syncthreads();
  if (jh == 0) {
#pragma unroll
    for (int ft = 0; ft < 4; ++ft)
#pragma unroll
      for (int reg = 0; reg < 4; ++reg)
        acc[ft][reg] += comb[(rt * 16 + q * 4 + reg) * 68 + ft * 16 + n16];
    if (n16 == 0) {
#pragma unroll
      for (int reg = 0; reg < 4; ++reg) {
        const int row = rt * 16 + q * 4 + reg;
        Zfull[row] = acc5[reg] + Zh1[row];
      }
    }
  }
  __syncthreads();
  if (jh == 0) {
#pragma unroll
    for (int reg = 0; reg < 4; ++reg) {
      const int row = rt * 16 + q * 4 + reg;
      const float invz = 1.f / Zfull[row];
      float* op = out + (size_t)(i0 + row) * OUT_FEAT + h * 64;
#pragma unroll
      for (int ft = 0; ft < 4; ++ft) op[ft * 16 + n16] = acc[ft][reg] * invz;
    }
  }
}

extern "C" void kernel_launch(void* const* d_in, const int* in_sizes, int n_in,
                              void* d_out, int out_size, void* d_ws, size_t ws_size,
                              hipStream_t stream) {
  const float* h   = (const float*)d_in[0];
  const float* adj = (const float*)d_in[1];
  const float* W   = (const float*)d_in[2];
  const float* a   = (const float*)d_in[3];
  float* out = (float*)d_out;

  char* ws = (char*)d_ws;
  _Float16* GT16 = (_Float16*)ws;                                         // 4 MB
  unsigned long long* bits = (unsigned long long*)(ws + 4u * 1024 * 1024);// 2 MB
  float* elT = (float*)(ws + 6u * 1024 * 1024);                           // 128 KB
  _Float16* eR1h = (_Float16*)(ws + 6u * 1024 * 1024 + 128 * 1024);       // 64 KB
  _Float16* eR2h = (_Float16*)(ws + 6u * 1024 * 1024 + 192 * 1024);       // 64 KB

  produce<<<dim3(64, 16), 256, 0, stream>>>(h, adj, W, a, GT16, elT, eR1h, eR2h, bits);
  attn_v7<<<dim3(128, 8), 256, 0, stream>>>(bits, GT16, elT, eR1h, eR2h, out);
}

// Round 13
// 156.078 us; speedup vs baseline: 1.6573x; 1.6573x over previous
//
#include <hip/hip_runtime.h>

#define N_NODES 4096
#define IN_FEAT 256
#define N_HEADS 8
#define N_HIDDEN 64
#define OUT_FEAT (N_HEADS * N_HIDDEN)  // 512
#define NEG_SLOPE 0.2f

typedef _Float16 half8 __attribute__((ext_vector_type(8)));
typedef _Float16 h2 __attribute__((ext_vector_type(2)));
typedef float floatx4 __attribute__((ext_vector_type(4)));

// ---------------- fat producer: MFMA GEMM + epilogue | adj->bits ----------
// (validated R8-R12 kernel, unchanged)
__global__ __launch_bounds__(256) void produce(
    const float* __restrict__ H, const float* __restrict__ adj,
    const float* __restrict__ Wt, const float* __restrict__ a,
    _Float16* __restrict__ GT16, float* __restrict__ elT,
    _Float16* __restrict__ eR1h, _Float16* __restrict__ eR2h,
    unsigned long long* __restrict__ bits) {
  __shared__ _Float16 SM[4 * 64 * 64];  // 32 KB: Ah|Al|Bh|Bl
  const int t = threadIdx.x;
  const int bx = blockIdx.x, by = blockIdx.y;

  if (by >= 8) {
    const int c = bx * 8 + (by - 8);
    const size_t W0 = (size_t)c * 512;
    const int wv = t >> 6, lane = t & 63;
    for (int k0 = 0; k0 < 128; k0 += 8) {
      float v[8];
#pragma unroll
      for (int k = 0; k < 8; ++k)
        v[k] = adj[(W0 + wv * 128 + k0 + k) * 64 + lane];
#pragma unroll
      for (int k = 0; k < 8; ++k) {
        unsigned long long m = __ballot(v[k] != 0.f);
        if (lane == 0) bits[W0 + wv * 128 + k0 + k] = m;
      }
    }
    return;
  }

  _Float16* Ah = SM;
  _Float16* Al = SM + 4096;
  _Float16* Bh = SM + 8192;
  _Float16* Bl = SM + 12288;
  const int w = t >> 6, l = t & 63;
  const int n16 = l & 15, q = l >> 4;
  const int bi = bx, bo = by;
  const int m0 = bi * 64 + w * 16;

  floatx4 acc[4];
#pragma unroll
  for (int ct = 0; ct < 4; ++ct) acc[ct] = (floatx4)0.f;

  for (int kc = 0; kc < 4; ++kc) {
    if (kc) __syncthreads();
#pragma unroll
    for (int p = 0; p < 4; ++p) {
      const int idx = p * 256 + t;
      const int r = idx >> 4;
      const int c4 = (idx & 15) << 2;
      const int dst = r * 64 + ((((idx & 15) >> 1)) ^ (r & 7)) * 8 + (idx & 1) * 4;
      float4 hv = *(const float4*)(H + (size_t)(bi * 64 + r) * IN_FEAT + kc * 64 + c4);
      float4 wv = *(const float4*)(Wt + (size_t)(bo * 64 + r) * IN_FEAT + kc * 64 + c4);
      union { _Float16 h[4]; int2 d; } hh_, hl_, wh_, wl_;
      hh_.h[0] = (_Float16)hv.x; hh_.h[1] = (_Float16)hv.y;
      hh_.h[2] = (_Float16)hv.z; hh_.h[3] = (_Float16)hv.w;
      hl_.h[0] = (_Float16)(hv.x - (float)hh_.h[0]);
      hl_.h[1] = (_Float16)(hv.y - (float)hh_.h[1]);
      hl_.h[2] = (_Float16)(hv.z - (float)hh_.h[2]);
      hl_.h[3] = (_Float16)(hv.w - (float)hh_.h[3]);
      wh_.h[0] = (_Float16)wv.x; wh_.h[1] = (_Float16)wv.y;
      wh_.h[2] = (_Float16)wv.z; wh_.h[3] = (_Float16)wv.w;
      wl_.h[0] = (_Float16)(wv.x - (float)wh_.h[0]);
      wl_.h[1] = (_Float16)(wv.y - (float)wh_.h[1]);
      wl_.h[2] = (_Float16)(wv.z - (float)wh_.h[2]);
      wl_.h[3] = (_Float16)(wv.w - (float)wh_.h[3]);
      *(int2*)&Ah[dst] = hh_.d;
      *(int2*)&Al[dst] = hl_.d;
      *(int2*)&Bh[dst] = wh_.d;
      *(int2*)&Bl[dst] = wl_.d;
    }
    __syncthreads();
#pragma unroll
    for (int ks = 0; ks < 2; ++ks) {
      const int ao = (w * 16 + n16) * 64 + (((ks << 2) + q) ^ (n16 & 7)) * 8;
      half8 Afh = *(const half8*)&Ah[ao];
      half8 Afl = *(const half8*)&Al[ao];
#pragma unroll
      for (int ct = 0; ct < 4; ++ct) {
        const int bofs = (ct * 16 + n16) * 64 + (((ks << 2) + q) ^ (n16 & 7)) * 8;
        half8 Bfh = *(const half8*)&Bh[bofs];
        half8 Bfl = *(const half8*)&Bl[bofs];
        acc[ct] = __builtin_amdgcn_mfma_f32_16x16x32_f16(Afh, Bfh, acc[ct], 0, 0, 0);
        acc[ct] = __builtin_amdgcn_mfma_f32_16x16x32_f16(Afl, Bfh, acc[ct], 0, 0, 0);
        acc[ct] = __builtin_amdgcn_mfma_f32_16x16x32_f16(Afh, Bfl, acc[ct], 0, 0, 0);
      }
    }
  }

  float aLv[4], aRv[4];
#pragma unroll
  for (int ct = 0; ct < 4; ++ct) {
    aLv[ct] = a[ct * 16 + n16];
    aRv[ct] = a[64 + ct * 16 + n16];
  }
#pragma unroll
  for (int reg = 0; reg < 4; ++reg) {
    float sl = 0.f, sr = 0.f;
#pragma unroll
    for (int ct = 0; ct < 4; ++ct) {
      sl = fmaf(acc[ct][reg], aLv[ct], sl);
      sr = fmaf(acc[ct][reg], aRv[ct], sr);
    }
#pragma unroll
    for (int off = 1; off < 16; off <<= 1) {
      sl += __shfl_xor(sl, off);
      sr += __shfl_xor(sr, off);
    }
    if (n16 == 0) {
      const int rowi = m0 + q * 4 + reg;
      elT[(size_t)bo * N_NODES + rowi] = sl;
      eR1h[(size_t)bo * N_NODES + rowi] = (_Float16)__expf(sr);
      eR2h[(size_t)bo * N_NODES + rowi] = (_Float16)__expf(0.2f * sr);
    }
  }

  __syncthreads();
  _Float16* LG = SM;  // 64 x 72 halfs
#pragma unroll
  for (int ct = 0; ct < 4; ++ct)
#pragma unroll
    for (int reg = 0; reg < 4; ++reg)
      LG[(w * 16 + q * 4 + reg) * 72 + ct * 16 + n16] = (_Float16)acc[ct][reg];
  __syncthreads();
  {
    const int f = t >> 2, jq = t & 3;
    union { _Float16 hh[16]; int4 v[2]; } u;
#pragma unroll
    for (int k = 0; k < 16; ++k) u.hh[k] = LG[(jq * 16 + k) * 72 + f];
    _Float16* dst = GT16 + (size_t)(bo * 64 + f) * N_NODES + bi * 64 + jq * 16;
    *(int4*)dst = u.v[0];
    *(int4*)(dst + 8) = u.v[1];
  }
}

// ---------------- dense attention v8: v6 loop + global_load_lds staging ---
// Grid (128 i-tiles, 8 heads), 256 threads = 4 waves: rt=w&1 (16 rows),
// jh=w>>1 (2048 j). Gt staged via __builtin_amdgcn_global_load_lds width=16
// (async, no VGPR transit). LDS dest is wave-uniform+lane*16, so the XOR
// swizzle is applied on the SOURCE side: lane picks global chunk
// cg = slot ^ (row&7). bits in per-lane registers (R12-validated addressing);
// eR staged via tiny register stores (v6). pk-fp16 P-gen + ones-column Z
// MFMA + jh-combine epilogue: validated v6/R12.
__global__ __launch_bounds__(256) void attn_v8(
    const unsigned long long* __restrict__ bits, const _Float16* __restrict__ GT16,
    const float* __restrict__ elT, const _Float16* __restrict__ eR1h,
    const _Float16* __restrict__ eR2h, float* __restrict__ out) {
  __shared__ __align__(16) _Float16 Gt[2][2][4096];   // [par][jh], 32 KB
  __shared__ __align__(16) _Float16 eRs1[2][2][64];   // 512 B
  __shared__ __align__(16) _Float16 eRs2[2][2][64];   // 512 B
  __shared__ float eL1s[32], eL2s[32];
  __shared__ float Zh1[32], Zfull[32];

  const int t = threadIdx.x;
  const int ib = blockIdx.x, h = blockIdx.y;
  const int i0 = ib * 32;
  const int w = t >> 6, l = t & 63, n16 = l & 15, q = l >> 4;
  const int rt = w & 1, jh = w >> 1;

  // ---- Gt staging descriptors: call c stages flat chunk w*256+c*64+l ----
  const _Float16* gsrcs[4];
  int ldsbase[4];  // half-offset of wave-uniform LDS base for call c
#pragma unroll
  for (int c = 0; c < 4; ++c) {
    const int flat = w * 256 + c * 64 + l;
    const int fjh = flat >> 9;
    const int ff = (flat >> 3) & 63;
    const int ss = flat & 7;
    const int cg = ss ^ (ff & 7);
    gsrcs[c] = GT16 + (size_t)(h * 64 + ff) * N_NODES + fjh * 2048 + cg * 8;
    ldsbase[c] = (w * 256 + c * 64) * 8;  // + lane*8 halfs implicit (lane*16B)
  }
  // eR staging role (t < 32): era selects eR1/eR2, erjh the j-half
  const int era = (t >> 3) & 1, erjh = t >> 4, erseg = t & 7;
  const _Float16* esrc0 = (era ? eR2h : eR1h) + (size_t)h * N_NODES + erjh * 2048 + erseg * 8;
  // bits: per-lane register stream (R12-validated addressing)
  const unsigned long long* bp = bits + (size_t)(i0 + rt * 16 + n16) * 64 + jh * 32;

  if (t < 32) {
    float e = elT[(size_t)h * N_NODES + i0 + t];
    eL1s[t] = __expf(e);
    eL2s[t] = __expf(0.2f * e);
  }
  // ---- stage step 0 into par=0 ----
#pragma unroll
  for (int c = 0; c < 4; ++c)
    __builtin_amdgcn_global_load_lds(
        (const __attribute__((address_space(1))) unsigned int*)gsrcs[c],
        (__attribute__((address_space(3))) unsigned int*)(&Gt[0][0][0] + ldsbase[c]),
        16, 0, 0);
  if (t < 32) {
    int4 ev = *(const int4*)esrc0;
    *(int4*)&(era ? eRs2 : eRs1)[0][erjh][erseg * 8] = ev;
  }
  unsigned long long bvc = bp[0];
  __syncthreads();

  const _Float16 e1f = (_Float16)eL1s[rt * 16 + n16];
  const _Float16 e2f = (_Float16)eL2s[rt * 16 + n16];
  const h2 eL1h2 = {e1f, e1f};
  const h2 eL2h2 = {e2f, e2f};
  half8 Bones;
#pragma unroll
  for (int k = 0; k < 8; ++k) Bones[k] = (n16 == 0) ? (_Float16)1.f : (_Float16)0.f;

  floatx4 acc[4];
#pragma unroll
  for (int ft = 0; ft < 4; ++ft) acc[ft] = (floatx4)0.f;
  floatx4 acc5 = (floatx4)0.f;

  int par = 0;
  for (int step = 0; step < 32; ++step) {
    // ---- async-stage step+1 into other parity (no VGPR transit) ----
    int4 ev;
    unsigned long long bvn = bvc;
    if (step + 1 < 32) {
      const int np = par ^ 1;
#pragma unroll
      for (int c = 0; c < 4; ++c)
        __builtin_amdgcn_global_load_lds(
            (const __attribute__((address_space(1))) unsigned int*)(gsrcs[c] + (step + 1) * 64),
            (__attribute__((address_space(3))) unsigned int*)(&Gt[np][0][0] + ldsbase[c]),
            16, 0, 0);
      if (t < 32) ev = *(const int4*)(esrc0 + (step + 1) * 64);
      bvn = bp[step + 1];
    }
    // ---- compute current step (validated v6 body) ----
    const _Float16* gt = &Gt[par][jh][0];
#pragma unroll
    for (int ks = 0; ks < 2; ++ks) {
      const unsigned dw = (unsigned)(bvc >> (ks * 32));
      const unsigned byte = (dw >> (q * 8)) & 0xffu;
      uint4 r1 = *(const uint4*)&eRs1[par][jh][ks * 32 + q * 8];
      uint4 r2 = *(const uint4*)&eRs2[par][jh][ks * 32 + q * 8];
      const unsigned r1a[4] = {r1.x, r1.y, r1.z, r1.w};
      const unsigned r2a[4] = {r2.x, r2.y, r2.z, r2.w};
      unsigned pr[4];
#pragma unroll
      for (int kk = 0; kk < 4; ++kk) {
        h2 pa = eL1h2 * __builtin_bit_cast(h2, r1a[kk]);
        h2 pb = eL2h2 * __builtin_bit_cast(h2, r2a[kk]);
        h2 pv = __builtin_elementwise_max(pa, pb);
        unsigned y = (byte >> (2 * kk)) & 3u;
        unsigned b01 = (y | (y << 15)) & 0x00010001u;
        unsigned keep = b01 * 0xffffu;
        pr[kk] = (__builtin_bit_cast(unsigned, pv) & keep) | (0x3C003C00u & ~keep);
      }
      const uint4 prv = {pr[0], pr[1], pr[2], pr[3]};
      half8 Af = __builtin_bit_cast(half8, prv);
#pragma unroll
      for (int ft = 0; ft < 4; ++ft) {
        half8 Bf = *(const half8*)&gt[(ft * 16 + n16) * 64 + (((ks << 2) + q) ^ (n16 & 7)) * 8];
        acc[ft] = __builtin_amdgcn_mfma_f32_16x16x32_f16(Af, Bf, acc[ft], 0, 0, 0);
      }
      acc5 = __builtin_amdgcn_mfma_f32_16x16x32_f16(Af, Bones, acc5, 0, 0, 0);
    }
    // ---- store staged eR regs; barrier drains global_load_lds + LDS ----
    if (step + 1 < 32 && t < 32)
      *(int4*)&(era ? eRs2 : eRs1)[par ^ 1][erjh][erseg * 8] = ev;
    bvc = bvn;
    __syncthreads();
    par ^= 1;
  }

  // ---- combine j-halves, normalize, store (validated v6 epilogue) ----
  float* comb = (float*)&Gt[0][0][0];  // 32 x 68 fp32 = 8.7 KB
  if (jh == 1) {
#pragma unroll
    for (int ft = 0; ft < 4; ++ft)
#pragma unroll
      for (int reg = 0; reg < 4; ++reg)
        comb[(rt * 16 + q * 4 + reg) * 68 + ft * 16 + n16] = acc[ft][reg];
    if (n16 == 0) {
#pragma unroll
      for (int reg = 0; reg < 4; ++reg) Zh1[rt * 16 + q * 4 + reg] = acc5[reg];
    }
  }
  __syncthreads();
  if (jh == 0) {
#pragma unroll
    for (int ft = 0; ft < 4; ++ft)
#pragma unroll
      for (int reg = 0; reg < 4; ++reg)
        acc[ft][reg] += comb[(rt * 16 + q * 4 + reg) * 68 + ft * 16 + n16];
    if (n16 == 0) {
#pragma unroll
      for (int reg = 0; reg < 4; ++reg) {
        const int row = rt * 16 + q * 4 + reg;
        Zfull[row] = acc5[reg] + Zh1[row];
      }
    }
  }
  __syncthreads();
  if (jh == 0) {
#pragma unroll
    for (int reg = 0; reg < 4; ++reg) {
      const int row = rt * 16 + q * 4 + reg;
      const float invz = 1.f / Zfull[row];
      float* op = out + (size_t)(i0 + row) * OUT_FEAT + h * 64;
#pragma unroll
      for (int ft = 0; ft < 4; ++ft) op[ft * 16 + n16] = acc[ft][reg] * invz;
    }
  }
}

extern "C" void kernel_launch(void* const* d_in, const int* in_sizes, int n_in,
                              void* d_out, int out_size, void* d_ws, size_t ws_size,
                              hipStream_t stream) {
  const float* h   = (const float*)d_in[0];
  const float* adj = (const float*)d_in[1];
  const float* W   = (const float*)d_in[2];
  const float* a   = (const float*)d_in[3];
  float* out = (float*)d_out;

  char* ws = (char*)d_ws;
  _Float16* GT16 = (_Float16*)ws;                                         // 4 MB
  unsigned long long* bits = (unsigned long long*)(ws + 4u * 1024 * 1024);// 2 MB
  float* elT = (float*)(ws + 6u * 1024 * 1024);                           // 128 KB
  _Float16* eR1h = (_Float16*)(ws + 6u * 1024 * 1024 + 128 * 1024);       // 64 KB
  _Float16* eR2h = (_Float16*)(ws + 6u * 1024 * 1024 + 192 * 1024);       // 64 KB

  produce<<<dim3(64, 16), 256, 0, stream>>>(h, adj, W, a, GT16, elT, eR1h, eR2h, bits);
  attn_v8<<<dim3(128, 8), 256, 0, stream>>>(bits, GT16, elT, eR1h, eR2h, out);
}